// Round 1
// baseline (604.240 us; speedup 1.0000x reference)
//
#include <hip/hip_runtime.h>
#include <math.h>

#define HD __device__ __forceinline__

// Problem dims (fixed by reference setup_inputs)
constexpr int TT = 2048;   // tokens = B*S
constexpr int HH = 1024;   // hidden
constexpr int II = 2816;   // intermediate
constexpr int EE = 8;      // experts

typedef short  bf16x8  __attribute__((ext_vector_type(8)));
typedef float  floatx4 __attribute__((ext_vector_type(4)));

// ---- workspace layout (bytes) ----
constexpr size_t OFF_XB    = 0;                        // [TT][HH] bf16      4,194,304
constexpr size_t OFF_WGT   = OFF_XB    + (size_t)TT*HH*2;
constexpr size_t OFF_WUT   = OFF_WGT   + (size_t)EE*II*HH*2;   // w_gate^T bf16 [E][I][H]
constexpr size_t OFF_WDT   = OFF_WUT   + (size_t)EE*II*HH*2;   // w_up^T
constexpr size_t OFF_ABUF  = OFF_WDT   + (size_t)EE*HH*II*2;   // w_down^T bf16 [E][H][I]
constexpr size_t OFF_CNT   = OFF_ABUF  + (size_t)2*TT*II*2;    // act buf [2T][I] bf16
constexpr size_t OFF_OFFS  = OFF_CNT   + 256;
constexpr size_t OFF_FILL  = OFF_OFFS  + 256;
constexpr size_t OFF_EMETA = OFF_FILL  + 256;                  // [T][2] int
constexpr size_t OFF_WMETA = OFF_EMETA + 16384;                // [T][2] float
constexpr size_t OFF_TLIST = OFF_WMETA + 16384;                // [2T] int
constexpr size_t OFF_GWL   = OFF_TLIST + 16384;                // [2T] float

HD unsigned short f2bf(float f) {
  union { float f; unsigned int u; } v; v.f = f;
  return (unsigned short)((v.u + 0x7fffu + ((v.u >> 16) & 1u)) >> 16);
}

HD void load_lds16(const void* gptr, void* lptr) {
  __builtin_amdgcn_global_load_lds(
      (const __attribute__((address_space(1))) void*)gptr,
      (__attribute__((address_space(3))) void*)lptr,
      16, 0, 0);
}

// ---------------- zero / convert ----------------
__global__ __launch_bounds__(256)
void zero_kernel(float* __restrict__ out, int n, int* __restrict__ counts, int* __restrict__ fill) {
  const int i = blockIdx.x * blockDim.x + threadIdx.x;
  if (i < EE) { counts[i] = 0; fill[i] = 0; }
  for (int idx = i; idx < n; idx += gridDim.x * blockDim.x) out[idx] = 0.f;
}

__global__ __launch_bounds__(256)
void convert_x_kernel(const float* __restrict__ x, unsigned short* __restrict__ xb, int n4) {
  const int i = blockIdx.x * blockDim.x + threadIdx.x;
  if (i < n4) {
    float4 v = ((const float4*)x)[i];
    ushort4 o;
    o.x = f2bf(v.x); o.y = f2bf(v.y); o.z = f2bf(v.z); o.w = f2bf(v.w);
    ((ushort4*)xb)[i] = o;
  }
}

// src: [E][R][C] fp32  ->  dst: [E][C][R] bf16. grid (C/64, R/64, E), block 256.
__global__ __launch_bounds__(256)
void transpose_cast_kernel(const float* __restrict__ src, unsigned short* __restrict__ dst,
                           int R, int C) {
  __shared__ float tile[64][65];
  const size_t base = (size_t)blockIdx.z * R * C;
  const int c0 = blockIdx.x * 64;
  const int r0 = blockIdx.y * 64;
  const int tx = threadIdx.x & 63;
  const int ty = threadIdx.x >> 6;   // 0..3
#pragma unroll
  for (int it = 0; it < 16; ++it) {
    const int r = it * 4 + ty;
    tile[r][tx] = src[base + (size_t)(r0 + r) * C + c0 + tx];
  }
  __syncthreads();
#pragma unroll
  for (int it = 0; it < 16; ++it) {
    const int c = it * 4 + ty;
    dst[base + (size_t)(c0 + c) * R + r0 + tx] = f2bf(tile[tx][c]);
  }
}

// ---------------- router (fp32, exact top-k semantics) ----------------
__global__ __launch_bounds__(64)
void router_kernel(const float* __restrict__ x, const float* __restrict__ w_router,
                   int* __restrict__ counts, int* __restrict__ emeta, float* __restrict__ wmeta) {
  const int t = blockIdx.x;
  const int lane = threadIdx.x;
  float acc[EE];
#pragma unroll
  for (int e = 0; e < EE; ++e) acc[e] = 0.f;
  for (int h = lane; h < HH; h += 64) {
    const float xv = x[(size_t)t * HH + h];
    const float* wr = w_router + (size_t)h * EE;
#pragma unroll
    for (int e = 0; e < EE; ++e) acc[e] += xv * wr[e];
  }
#pragma unroll
  for (int e = 0; e < EE; ++e) {
#pragma unroll
    for (int off = 32; off > 0; off >>= 1) acc[e] += __shfl_xor(acc[e], off, 64);
  }
  if (lane == 0) {
    // top-2, stable tie-break to lower index (matches jax.lax.top_k)
    int e0 = 0; float v0 = acc[0];
#pragma unroll
    for (int e = 1; e < EE; ++e) if (acc[e] > v0) { v0 = acc[e]; e0 = e; }
    int e1 = -1; float v1 = -3.4e38f;
#pragma unroll
    for (int e = 0; e < EE; ++e) if (e != e0 && acc[e] > v1) { v1 = acc[e]; e1 = e; }
    const float ex = __expf(v1 - v0);
    const float s  = 1.f + ex;
    emeta[2 * t] = e0; emeta[2 * t + 1] = e1;
    wmeta[2 * t] = 1.f / s; wmeta[2 * t + 1] = ex / s;
    atomicAdd(&counts[e0], 1);
    atomicAdd(&counts[e1], 1);
  }
}

__global__ void scan_kernel(const int* __restrict__ counts, int* __restrict__ offsets) {
  if (threadIdx.x == 0 && blockIdx.x == 0) {
    int s = 0;
    for (int e = 0; e < EE; ++e) { offsets[e] = s; s += counts[e]; }
    offsets[EE] = s;
  }
}

__global__ __launch_bounds__(256)
void fill_kernel(const int* __restrict__ emeta, const float* __restrict__ wmeta,
                 const int* __restrict__ offsets, int* __restrict__ fill,
                 int* __restrict__ token_list, float* __restrict__ gw_list) {
  const int t = blockIdx.x * blockDim.x + threadIdx.x;
  if (t >= TT) return;
#pragma unroll
  for (int s = 0; s < 2; ++s) {
    const int e = emeta[2 * t + s];
    const int pos = atomicAdd(&fill[e], 1);
    token_list[offsets[e] + pos] = t;
    gw_list[offsets[e] + pos] = wmeta[2 * t + s];
  }
}

// ---------------- GEMM1: A = silu(X Wg) * (X Wu), per expert, gathered rows ----------------
// X bf16 [T][H] gathered; Wg^T/Wu^T bf16 [E][I][H]; out Abuf bf16 [2T][I] (compact rows).
__global__ __launch_bounds__(256, 1)
void gemm1_kernel(const unsigned short* __restrict__ xb,
                  const unsigned short* __restrict__ wgt,
                  const unsigned short* __restrict__ wut,
                  const int* __restrict__ offsets,
                  const int* __restrict__ token_list,
                  unsigned short* __restrict__ Abuf) {
  const int e = blockIdx.z;
  const int off_e = offsets[e];
  const int n_e = offsets[e + 1] - off_e;
  const int m_base = blockIdx.y * 128;
  if (m_base >= n_e) return;
  const int n_base = blockIdx.x * 128;   // I dimension

  __shared__ __attribute__((aligned(16))) unsigned short ldsA[128 * 64];
  __shared__ __attribute__((aligned(16))) unsigned short ldsG[128 * 64];
  __shared__ __attribute__((aligned(16))) unsigned short ldsU[128 * 64];

  const int tid = threadIdx.x;
  const int wave = tid >> 6;
  const int lane = tid & 63;
  const int quad = lane >> 4;
  const int l16 = lane & 15;
  const int wave_m = (wave & 1) * 64;
  const int wave_n = (wave >> 1) * 64;

  const int srow = lane >> 3;               // 0..7
  const int clog = (lane & 7) ^ srow;       // xor-swizzled logical 16B chunk

  const unsigned short* gA[4];
  const unsigned short* gG[4];
  const unsigned short* gU[4];
#pragma unroll
  for (int it = 0; it < 4; ++it) {
    const int r = it * 32 + wave * 8 + srow;
    int ar = m_base + r; if (ar > n_e - 1) ar = n_e - 1;
    const int tok = token_list[off_e + ar];
    gA[it] = xb + (size_t)tok * HH + clog * 8;
    gG[it] = wgt + ((size_t)e * II + (n_base + r)) * HH + clog * 8;
    gU[it] = wut + ((size_t)e * II + (n_base + r)) * HH + clog * 8;
  }

  floatx4 accG[4][4], accU[4][4];
  const floatx4 fz = {0.f, 0.f, 0.f, 0.f};
#pragma unroll
  for (int i = 0; i < 4; ++i)
#pragma unroll
    for (int j = 0; j < 4; ++j) { accG[i][j] = fz; accU[i][j] = fz; }

  for (int kt = 0; kt < HH / 64; ++kt) {
    const int k0 = kt * 64;
#pragma unroll
    for (int it = 0; it < 4; ++it) {
      const int lbase = (it * 32 + wave * 8) * 64;
      load_lds16(gA[it] + k0, &ldsA[lbase]);
      load_lds16(gG[it] + k0, &ldsG[lbase]);
      load_lds16(gU[it] + k0, &ldsU[lbase]);
    }
    __syncthreads();
#pragma unroll
    for (int ks = 0; ks < 2; ++ks) {
      bf16x8 af[4], bg[4], bu[4];
#pragma unroll
      for (int f = 0; f < 4; ++f) {
        const int rowA = wave_m + f * 16 + l16;
        const int cA = (ks * 4 + quad) ^ (rowA & 7);
        af[f] = *(const bf16x8*)&ldsA[rowA * 64 + cA * 8];
        const int rowB = wave_n + f * 16 + l16;
        const int cB = (ks * 4 + quad) ^ (rowB & 7);
        bg[f] = *(const bf16x8*)&ldsG[rowB * 64 + cB * 8];
        bu[f] = *(const bf16x8*)&ldsU[rowB * 64 + cB * 8];
      }
#pragma unroll
      for (int mf = 0; mf < 4; ++mf)
#pragma unroll
        for (int nf = 0; nf < 4; ++nf) {
          accG[mf][nf] = __builtin_amdgcn_mfma_f32_16x16x32_bf16(af[mf], bg[nf], accG[mf][nf], 0, 0, 0);
          accU[mf][nf] = __builtin_amdgcn_mfma_f32_16x16x32_bf16(af[mf], bu[nf], accU[mf][nf], 0, 0, 0);
        }
    }
    __syncthreads();
  }

  // epilogue: a = silu(g)*u -> bf16, compact row = off_e + m_base + tile_row
#pragma unroll
  for (int mf = 0; mf < 4; ++mf)
#pragma unroll
    for (int nf = 0; nf < 4; ++nf) {
      const int col = n_base + wave_n + nf * 16 + l16;
#pragma unroll
      for (int j = 0; j < 4; ++j) {
        const int r = m_base + wave_m + mf * 16 + quad * 4 + j;
        if (r < n_e) {
          const float g = accG[mf][nf][j];
          const float u = accU[mf][nf][j];
          const float a = (g / (1.f + __expf(-g))) * u;
          Abuf[(size_t)(off_e + r) * II + col] = f2bf(a);
        }
      }
    }
}

// ---------------- GEMM2: Y = A Wd^T, scatter out += gw*(Y + b_down) ----------------
__global__ __launch_bounds__(256, 1)
void gemm2_kernel(const unsigned short* __restrict__ Abuf,
                  const unsigned short* __restrict__ wdt,   // [E][H][I] bf16
                  const float* __restrict__ b_down,         // [E][H] fp32
                  const int* __restrict__ offsets,
                  const int* __restrict__ token_list,
                  const float* __restrict__ gw_list,
                  float* __restrict__ out) {
  const int e = blockIdx.z;
  const int off_e = offsets[e];
  const int n_e = offsets[e + 1] - off_e;
  const int m_base = blockIdx.y * 128;
  if (m_base >= n_e) return;
  const int n_base = blockIdx.x * 128;   // H dimension

  __shared__ __attribute__((aligned(16))) unsigned short ldsA[128 * 64];
  __shared__ __attribute__((aligned(16))) unsigned short ldsB[128 * 64];

  const int tid = threadIdx.x;
  const int wave = tid >> 6;
  const int lane = tid & 63;
  const int quad = lane >> 4;
  const int l16 = lane & 15;
  const int wave_m = (wave & 1) * 64;
  const int wave_n = (wave >> 1) * 64;

  const int srow = lane >> 3;
  const int clog = (lane & 7) ^ srow;

  const unsigned short* gA[4];
  const unsigned short* gB[4];
#pragma unroll
  for (int it = 0; it < 4; ++it) {
    const int r = it * 32 + wave * 8 + srow;
    int ar = m_base + r; if (ar > n_e - 1) ar = n_e - 1;
    gA[it] = Abuf + (size_t)(off_e + ar) * II + clog * 8;
    gB[it] = wdt + ((size_t)e * HH + (n_base + r)) * II + clog * 8;
  }

  floatx4 acc[4][4];
  const floatx4 fz = {0.f, 0.f, 0.f, 0.f};
#pragma unroll
  for (int i = 0; i < 4; ++i)
#pragma unroll
    for (int j = 0; j < 4; ++j) acc[i][j] = fz;

  for (int kt = 0; kt < II / 64; ++kt) {
    const int k0 = kt * 64;
#pragma unroll
    for (int it = 0; it < 4; ++it) {
      const int lbase = (it * 32 + wave * 8) * 64;
      load_lds16(gA[it] + k0, &ldsA[lbase]);
      load_lds16(gB[it] + k0, &ldsB[lbase]);
    }
    __syncthreads();
#pragma unroll
    for (int ks = 0; ks < 2; ++ks) {
      bf16x8 af[4], bf[4];
#pragma unroll
      for (int f = 0; f < 4; ++f) {
        const int rowA = wave_m + f * 16 + l16;
        const int cA = (ks * 4 + quad) ^ (rowA & 7);
        af[f] = *(const bf16x8*)&ldsA[rowA * 64 + cA * 8];
        const int rowB = wave_n + f * 16 + l16;
        const int cB = (ks * 4 + quad) ^ (rowB & 7);
        bf[f] = *(const bf16x8*)&ldsB[rowB * 64 + cB * 8];
      }
#pragma unroll
      for (int mf = 0; mf < 4; ++mf)
#pragma unroll
        for (int nf = 0; nf < 4; ++nf)
          acc[mf][nf] = __builtin_amdgcn_mfma_f32_16x16x32_bf16(af[mf], bf[nf], acc[mf][nf], 0, 0, 0);
    }
    __syncthreads();
  }

#pragma unroll
  for (int mf = 0; mf < 4; ++mf)
#pragma unroll
    for (int nf = 0; nf < 4; ++nf) {
      const int col = n_base + wave_n + nf * 16 + l16;
#pragma unroll
      for (int j = 0; j < 4; ++j) {
        const int r = m_base + wave_m + mf * 16 + quad * 4 + j;
        if (r < n_e) {
          const int cr = off_e + r;
          const int tok = token_list[cr];
          const float gw = gw_list[cr];
          atomicAdd(&out[(size_t)tok * HH + col],
                    gw * (acc[mf][nf][j] + b_down[e * HH + col]));
        }
      }
    }
}

// ---------------- launch ----------------
extern "C" void kernel_launch(void* const* d_in, const int* in_sizes, int n_in,
                              void* d_out, int out_size, void* d_ws, size_t ws_size,
                              hipStream_t stream) {
  const float* x        = (const float*)d_in[0];
  const float* w_router = (const float*)d_in[1];
  const float* w_gate   = (const float*)d_in[2];
  const float* w_up     = (const float*)d_in[3];
  const float* w_down   = (const float*)d_in[4];
  const float* b_down   = (const float*)d_in[5];
  float* out = (float*)d_out;

  char* ws = (char*)d_ws;
  unsigned short* xb   = (unsigned short*)(ws + OFF_XB);
  unsigned short* wgt  = (unsigned short*)(ws + OFF_WGT);
  unsigned short* wut  = (unsigned short*)(ws + OFF_WUT);
  unsigned short* wdt  = (unsigned short*)(ws + OFF_WDT);
  unsigned short* Abuf = (unsigned short*)(ws + OFF_ABUF);
  int*   counts  = (int*)(ws + OFF_CNT);
  int*   offsets = (int*)(ws + OFF_OFFS);
  int*   fill    = (int*)(ws + OFF_FILL);
  int*   emeta   = (int*)(ws + OFF_EMETA);
  float* wmeta   = (float*)(ws + OFF_WMETA);
  int*   tlist   = (int*)(ws + OFF_TLIST);
  float* gwl     = (float*)(ws + OFF_GWL);

  zero_kernel<<<2048, 256, 0, stream>>>(out, TT * HH, counts, fill);
  convert_x_kernel<<<(TT * HH / 4 + 255) / 256, 256, 0, stream>>>(x, xb, TT * HH / 4);
  transpose_cast_kernel<<<dim3(II / 64, HH / 64, EE), 256, 0, stream>>>(w_gate, wgt, HH, II);
  transpose_cast_kernel<<<dim3(II / 64, HH / 64, EE), 256, 0, stream>>>(w_up,   wut, HH, II);
  transpose_cast_kernel<<<dim3(HH / 64, II / 64, EE), 256, 0, stream>>>(w_down, wdt, II, HH);
  router_kernel<<<TT, 64, 0, stream>>>(x, w_router, counts, emeta, wmeta);
  scan_kernel<<<1, 64, 0, stream>>>(counts, offsets);
  fill_kernel<<<TT / 256, 256, 0, stream>>>(emeta, wmeta, offsets, fill, tlist, gwl);
  gemm1_kernel<<<dim3(II / 128, TT / 128, EE), 256, 0, stream>>>(xb, wgt, wut, offsets, tlist, Abuf);
  gemm2_kernel<<<dim3(HH / 128, TT / 128, EE), 256, 0, stream>>>(Abuf, wdt, b_down, offsets, tlist, gwl, out);
}

// Round 2
// 488.546 us; speedup vs baseline: 1.2368x; 1.2368x over previous
//
#include <hip/hip_runtime.h>
#include <math.h>

#define HD __device__ __forceinline__

// Problem dims (fixed by reference setup_inputs)
constexpr int TT = 2048;   // tokens = B*S
constexpr int HH = 1024;   // hidden
constexpr int II = 2816;   // intermediate
constexpr int EE = 8;      // experts

typedef short  bf16x8  __attribute__((ext_vector_type(8)));
typedef float  floatx4 __attribute__((ext_vector_type(4)));

// ---- workspace layout (bytes) ----
constexpr size_t OFF_XB    = 0;                        // [TT][HH] bf16
constexpr size_t OFF_WGT   = OFF_XB    + (size_t)TT*HH*2;
constexpr size_t OFF_WUT   = OFF_WGT   + (size_t)EE*II*HH*2;   // w_gate^T bf16 [E][I][H]
constexpr size_t OFF_WDT   = OFF_WUT   + (size_t)EE*II*HH*2;   // w_up^T
constexpr size_t OFF_ABUF  = OFF_WDT   + (size_t)EE*HH*II*2;   // w_down^T bf16 [E][H][I]
constexpr size_t OFF_CNT   = OFF_ABUF  + (size_t)2*TT*II*2;    // act buf [2T][I] bf16
constexpr size_t OFF_OFFS  = OFF_CNT   + 256;
constexpr size_t OFF_FILL  = OFF_OFFS  + 256;
constexpr size_t OFF_MDESC = OFF_FILL  + 256;                  // [1+39] int tile descriptors
constexpr size_t OFF_EMETA = OFF_MDESC + 256;                  // [T][2] int
constexpr size_t OFF_WMETA = OFF_EMETA + 16384;                // [T][2] float
constexpr size_t OFF_TLIST = OFF_WMETA + 16384;                // [2T] int
constexpr size_t OFF_GWL   = OFF_TLIST + 16384;                // [2T] float

HD unsigned short f2bf(float f) {
  union { float f; unsigned int u; } v; v.f = f;
  return (unsigned short)((v.u + 0x7fffu + ((v.u >> 16) & 1u)) >> 16);
}

HD void load_lds16(const void* gptr, void* lptr) {
  __builtin_amdgcn_global_load_lds(
      (const __attribute__((address_space(1))) void*)gptr,
      (__attribute__((address_space(3))) void*)lptr,
      16, 0, 0);
}

// ---------------- zero / convert ----------------
__global__ __launch_bounds__(256)
void zero_kernel(float* __restrict__ out, int n4, int* __restrict__ counts, int* __restrict__ fill) {
  const int i = blockIdx.x * blockDim.x + threadIdx.x;
  if (i < EE) { counts[i] = 0; fill[i] = 0; }
  const float4 z = {0.f, 0.f, 0.f, 0.f};
  for (int idx = i; idx < n4; idx += gridDim.x * blockDim.x) ((float4*)out)[idx] = z;
}

__global__ __launch_bounds__(256)
void convert_x_kernel(const float* __restrict__ x, unsigned short* __restrict__ xb, int n4) {
  const int i = blockIdx.x * blockDim.x + threadIdx.x;
  if (i < n4) {
    float4 v = ((const float4*)x)[i];
    ushort4 o;
    o.x = f2bf(v.x); o.y = f2bf(v.y); o.z = f2bf(v.z); o.w = f2bf(v.w);
    ((ushort4*)xb)[i] = o;
  }
}

// src: [E][R][C] fp32  ->  dst: [E][C][R] bf16. grid (C/64, R/64, E), block 256.
// float4 global loads, ushort4 global stores, <=2-way LDS conflicts (free).
__global__ __launch_bounds__(256)
void transpose_cast_kernel(const float* __restrict__ src, unsigned short* __restrict__ dst,
                           int R, int C) {
  __shared__ float tile[64][65];
  const size_t base = (size_t)blockIdx.z * R * C;
  const int c0 = blockIdx.x * 64;
  const int r0 = blockIdx.y * 64;
  const int sub = threadIdx.x >> 4;    // 0..15
  const int q   = threadIdx.x & 15;    // 0..15
#pragma unroll
  for (int it = 0; it < 4; ++it) {
    const int r = it * 16 + sub;
    const float4 v = *(const float4*)&src[base + (size_t)(r0 + r) * C + c0 + q * 4];
    tile[r][q * 4 + 0] = v.x; tile[r][q * 4 + 1] = v.y;
    tile[r][q * 4 + 2] = v.z; tile[r][q * 4 + 3] = v.w;
  }
  __syncthreads();
#pragma unroll
  for (int it = 0; it < 4; ++it) {
    const int c = it * 16 + sub;
    ushort4 o;
    o.x = f2bf(tile[q * 4 + 0][c]); o.y = f2bf(tile[q * 4 + 1][c]);
    o.z = f2bf(tile[q * 4 + 2][c]); o.w = f2bf(tile[q * 4 + 3][c]);
    *(ushort4*)&dst[base + (size_t)(c0 + c) * R + r0 + q * 4] = o;
  }
}

// ---------------- router (fp32, exact top-k semantics) ----------------
__global__ __launch_bounds__(64)
void router_kernel(const float* __restrict__ x, const float* __restrict__ w_router,
                   int* __restrict__ counts, int* __restrict__ emeta, float* __restrict__ wmeta) {
  const int t = blockIdx.x;
  const int lane = threadIdx.x;
  float acc[EE];
#pragma unroll
  for (int e = 0; e < EE; ++e) acc[e] = 0.f;
  for (int h = lane; h < HH; h += 64) {
    const float xv = x[(size_t)t * HH + h];
    const float* wr = w_router + (size_t)h * EE;
#pragma unroll
    for (int e = 0; e < EE; ++e) acc[e] += xv * wr[e];
  }
#pragma unroll
  for (int e = 0; e < EE; ++e) {
#pragma unroll
    for (int off = 32; off > 0; off >>= 1) acc[e] += __shfl_xor(acc[e], off, 64);
  }
  if (lane == 0) {
    int e0 = 0; float v0 = acc[0];
#pragma unroll
    for (int e = 1; e < EE; ++e) if (acc[e] > v0) { v0 = acc[e]; e0 = e; }
    int e1 = -1; float v1 = -3.4e38f;
#pragma unroll
    for (int e = 0; e < EE; ++e) if (e != e0 && acc[e] > v1) { v1 = acc[e]; e1 = e; }
    const float ex = __expf(v1 - v0);
    const float s  = 1.f + ex;
    emeta[2 * t] = e0; emeta[2 * t + 1] = e1;
    wmeta[2 * t] = 1.f / s; wmeta[2 * t + 1] = ex / s;
    atomicAdd(&counts[e0], 1);
    atomicAdd(&counts[e1], 1);
  }
}

// offsets + m-tile descriptor list: mdesc[0]=count, mdesc[1+i] = (e<<20)|m_base
__global__ void scan_kernel(const int* __restrict__ counts, int* __restrict__ offsets,
                            int* __restrict__ mdesc) {
  if (threadIdx.x == 0 && blockIdx.x == 0) {
    int s = 0;
    for (int e = 0; e < EE; ++e) { offsets[e] = s; s += counts[e]; }
    offsets[EE] = s;
    int nt = 0;
    for (int e = 0; e < EE; ++e)
      for (int m = 0; m < counts[e]; m += 128) mdesc[1 + nt++] = (e << 20) | m;
    mdesc[0] = nt;
  }
}

__global__ __launch_bounds__(256)
void fill_kernel(const int* __restrict__ emeta, const float* __restrict__ wmeta,
                 const int* __restrict__ offsets, int* __restrict__ fill,
                 int* __restrict__ token_list, float* __restrict__ gw_list) {
  const int t = blockIdx.x * blockDim.x + threadIdx.x;
  if (t >= TT) return;
#pragma unroll
  for (int s = 0; s < 2; ++s) {
    const int e = emeta[2 * t + s];
    const int pos = atomicAdd(&fill[e], 1);
    token_list[offsets[e] + pos] = t;
    gw_list[offsets[e] + pos] = wmeta[2 * t + s];
  }
}

// ---------------- GEMM1: A = silu(X Wg) * (X Wu); 128x64 tile, dual acc ----------------
__global__ __launch_bounds__(256, 4)
void gemm1_kernel(const unsigned short* __restrict__ xb,
                  const unsigned short* __restrict__ wgt,
                  const unsigned short* __restrict__ wut,
                  const int* __restrict__ offsets,
                  const int* __restrict__ mdesc,
                  const int* __restrict__ token_list,
                  unsigned short* __restrict__ Abuf) {
  if ((int)blockIdx.y >= mdesc[0]) return;
  const int d = mdesc[1 + blockIdx.y];
  const int e = d >> 20;
  const int m_base = d & 0xFFFFF;
  const int off_e = offsets[e];
  const int n_e = offsets[e + 1] - off_e;
  const int n_base = blockIdx.x * 64;   // I dimension

  __shared__ __attribute__((aligned(16))) unsigned short ldsA[128 * 64];
  __shared__ __attribute__((aligned(16))) unsigned short ldsG[64 * 64];
  __shared__ __attribute__((aligned(16))) unsigned short ldsU[64 * 64];

  const int tid = threadIdx.x;
  const int wave = tid >> 6;
  const int lane = tid & 63;
  const int quad = lane >> 4;
  const int l16 = lane & 15;
  const int wave_m = (wave & 1) * 64;
  const int wave_n = (wave >> 1) * 32;

  const int srow = lane >> 3;               // 0..7
  const int clog = (lane & 7) ^ srow;       // xor-swizzled 16B chunk

  const unsigned short* gA[4];
  const unsigned short* gG[2];
  const unsigned short* gU[2];
#pragma unroll
  for (int it = 0; it < 4; ++it) {
    const int r = it * 32 + wave * 8 + srow;
    int ar = m_base + r; if (ar > n_e - 1) ar = n_e - 1;
    const int tok = token_list[off_e + ar];
    gA[it] = xb + (size_t)tok * HH + clog * 8;
  }
#pragma unroll
  for (int it = 0; it < 2; ++it) {
    const int r = it * 32 + wave * 8 + srow;
    gG[it] = wgt + ((size_t)e * II + (n_base + r)) * HH + clog * 8;
    gU[it] = wut + ((size_t)e * II + (n_base + r)) * HH + clog * 8;
  }

  floatx4 accG[4][2], accU[4][2];
  const floatx4 fz = {0.f, 0.f, 0.f, 0.f};
#pragma unroll
  for (int i = 0; i < 4; ++i)
#pragma unroll
    for (int j = 0; j < 2; ++j) { accG[i][j] = fz; accU[i][j] = fz; }

  for (int kt = 0; kt < HH / 64; ++kt) {
    const int k0 = kt * 64;
#pragma unroll
    for (int it = 0; it < 4; ++it)
      load_lds16(gA[it] + k0, &ldsA[(it * 32 + wave * 8) * 64]);
#pragma unroll
    for (int it = 0; it < 2; ++it) {
      load_lds16(gG[it] + k0, &ldsG[(it * 32 + wave * 8) * 64]);
      load_lds16(gU[it] + k0, &ldsU[(it * 32 + wave * 8) * 64]);
    }
    __syncthreads();
#pragma unroll
    for (int ks = 0; ks < 2; ++ks) {
      bf16x8 af[4], bg[2], bu[2];
#pragma unroll
      for (int f = 0; f < 4; ++f) {
        const int rowA = wave_m + f * 16 + l16;
        const int cA = (ks * 4 + quad) ^ (rowA & 7);
        af[f] = *(const bf16x8*)&ldsA[rowA * 64 + cA * 8];
      }
#pragma unroll
      for (int f = 0; f < 2; ++f) {
        const int rowB = wave_n + f * 16 + l16;
        const int cB = (ks * 4 + quad) ^ (rowB & 7);
        bg[f] = *(const bf16x8*)&ldsG[rowB * 64 + cB * 8];
        bu[f] = *(const bf16x8*)&ldsU[rowB * 64 + cB * 8];
      }
#pragma unroll
      for (int mf = 0; mf < 4; ++mf)
#pragma unroll
        for (int nf = 0; nf < 2; ++nf) {
          accG[mf][nf] = __builtin_amdgcn_mfma_f32_16x16x32_bf16(af[mf], bg[nf], accG[mf][nf], 0, 0, 0);
          accU[mf][nf] = __builtin_amdgcn_mfma_f32_16x16x32_bf16(af[mf], bu[nf], accU[mf][nf], 0, 0, 0);
        }
    }
    __syncthreads();
  }

#pragma unroll
  for (int mf = 0; mf < 4; ++mf)
#pragma unroll
    for (int nf = 0; nf < 2; ++nf) {
      const int col = n_base + wave_n + nf * 16 + l16;
#pragma unroll
      for (int j = 0; j < 4; ++j) {
        const int r = m_base + wave_m + mf * 16 + quad * 4 + j;
        if (r < n_e) {
          const float g = accG[mf][nf][j];
          const float u = accU[mf][nf][j];
          const float a = (g / (1.f + __expf(-g))) * u;
          Abuf[(size_t)(off_e + r) * II + col] = f2bf(a);
        }
      }
    }
}

// ---------------- GEMM2: Y = A Wd^T; 128x64 tile; scatter out += gw*(Y+b) ----------------
__global__ __launch_bounds__(256, 4)
void gemm2_kernel(const unsigned short* __restrict__ Abuf,
                  const unsigned short* __restrict__ wdt,   // [E][H][I] bf16
                  const float* __restrict__ b_down,         // [E][H] fp32
                  const int* __restrict__ offsets,
                  const int* __restrict__ mdesc,
                  const int* __restrict__ token_list,
                  const float* __restrict__ gw_list,
                  float* __restrict__ out) {
  if ((int)blockIdx.y >= mdesc[0]) return;
  const int d = mdesc[1 + blockIdx.y];
  const int e = d >> 20;
  const int m_base = d & 0xFFFFF;
  const int off_e = offsets[e];
  const int n_e = offsets[e + 1] - off_e;
  const int n_base = blockIdx.x * 64;   // H dimension

  __shared__ __attribute__((aligned(16))) unsigned short ldsA[128 * 64];
  __shared__ __attribute__((aligned(16))) unsigned short ldsB[64 * 64];

  const int tid = threadIdx.x;
  const int wave = tid >> 6;
  const int lane = tid & 63;
  const int quad = lane >> 4;
  const int l16 = lane & 15;
  const int wave_m = (wave & 1) * 64;
  const int wave_n = (wave >> 1) * 32;

  const int srow = lane >> 3;
  const int clog = (lane & 7) ^ srow;

  const unsigned short* gA[4];
  const unsigned short* gB[2];
#pragma unroll
  for (int it = 0; it < 4; ++it) {
    const int r = it * 32 + wave * 8 + srow;
    int ar = m_base + r; if (ar > n_e - 1) ar = n_e - 1;
    gA[it] = Abuf + (size_t)(off_e + ar) * II + clog * 8;
  }
#pragma unroll
  for (int it = 0; it < 2; ++it) {
    const int r = it * 32 + wave * 8 + srow;
    gB[it] = wdt + ((size_t)e * HH + (n_base + r)) * II + clog * 8;
  }

  floatx4 acc[4][2];
  const floatx4 fz = {0.f, 0.f, 0.f, 0.f};
#pragma unroll
  for (int i = 0; i < 4; ++i)
#pragma unroll
    for (int j = 0; j < 2; ++j) acc[i][j] = fz;

  for (int kt = 0; kt < II / 64; ++kt) {
    const int k0 = kt * 64;
#pragma unroll
    for (int it = 0; it < 4; ++it)
      load_lds16(gA[it] + k0, &ldsA[(it * 32 + wave * 8) * 64]);
#pragma unroll
    for (int it = 0; it < 2; ++it)
      load_lds16(gB[it] + k0, &ldsB[(it * 32 + wave * 8) * 64]);
    __syncthreads();
#pragma unroll
    for (int ks = 0; ks < 2; ++ks) {
      bf16x8 af[4], bf[2];
#pragma unroll
      for (int f = 0; f < 4; ++f) {
        const int rowA = wave_m + f * 16 + l16;
        const int cA = (ks * 4 + quad) ^ (rowA & 7);
        af[f] = *(const bf16x8*)&ldsA[rowA * 64 + cA * 8];
      }
#pragma unroll
      for (int f = 0; f < 2; ++f) {
        const int rowB = wave_n + f * 16 + l16;
        const int cB = (ks * 4 + quad) ^ (rowB & 7);
        bf[f] = *(const bf16x8*)&ldsB[rowB * 64 + cB * 8];
      }
#pragma unroll
      for (int mf = 0; mf < 4; ++mf)
#pragma unroll
        for (int nf = 0; nf < 2; ++nf)
          acc[mf][nf] = __builtin_amdgcn_mfma_f32_16x16x32_bf16(af[mf], bf[nf], acc[mf][nf], 0, 0, 0);
    }
    __syncthreads();
  }

#pragma unroll
  for (int mf = 0; mf < 4; ++mf)
#pragma unroll
    for (int nf = 0; nf < 2; ++nf) {
      const int col = n_base + wave_n + nf * 16 + l16;
#pragma unroll
      for (int j = 0; j < 4; ++j) {
        const int r = m_base + wave_m + mf * 16 + quad * 4 + j;
        if (r < n_e) {
          const int cr = off_e + r;
          const int tok = token_list[cr];
          const float gw = gw_list[cr];
          atomicAdd(&out[(size_t)tok * HH + col],
                    gw * (acc[mf][nf][j] + b_down[e * HH + col]));
        }
      }
    }
}

// ---------------- launch ----------------
extern "C" void kernel_launch(void* const* d_in, const int* in_sizes, int n_in,
                              void* d_out, int out_size, void* d_ws, size_t ws_size,
                              hipStream_t stream) {
  const float* x        = (const float*)d_in[0];
  const float* w_router = (const float*)d_in[1];
  const float* w_gate   = (const float*)d_in[2];
  const float* w_up     = (const float*)d_in[3];
  const float* w_down   = (const float*)d_in[4];
  const float* b_down   = (const float*)d_in[5];
  float* out = (float*)d_out;

  char* ws = (char*)d_ws;
  unsigned short* xb   = (unsigned short*)(ws + OFF_XB);
  unsigned short* wgt  = (unsigned short*)(ws + OFF_WGT);
  unsigned short* wut  = (unsigned short*)(ws + OFF_WUT);
  unsigned short* wdt  = (unsigned short*)(ws + OFF_WDT);
  unsigned short* Abuf = (unsigned short*)(ws + OFF_ABUF);
  int*   counts  = (int*)(ws + OFF_CNT);
  int*   offsets = (int*)(ws + OFF_OFFS);
  int*   fill    = (int*)(ws + OFF_FILL);
  int*   mdesc   = (int*)(ws + OFF_MDESC);
  int*   emeta   = (int*)(ws + OFF_EMETA);
  float* wmeta   = (float*)(ws + OFF_WMETA);
  int*   tlist   = (int*)(ws + OFF_TLIST);
  float* gwl     = (float*)(ws + OFF_GWL);

  zero_kernel<<<512, 256, 0, stream>>>(out, TT * HH / 4, counts, fill);
  convert_x_kernel<<<(TT * HH / 4 + 255) / 256, 256, 0, stream>>>(x, xb, TT * HH / 4);
  transpose_cast_kernel<<<dim3(II / 64, HH / 64, EE), 256, 0, stream>>>(w_gate, wgt, HH, II);
  transpose_cast_kernel<<<dim3(II / 64, HH / 64, EE), 256, 0, stream>>>(w_up,   wut, HH, II);
  transpose_cast_kernel<<<dim3(HH / 64, II / 64, EE), 256, 0, stream>>>(w_down, wdt, II, HH);
  router_kernel<<<TT, 64, 0, stream>>>(x, w_router, counts, emeta, wmeta);
  scan_kernel<<<1, 64, 0, stream>>>(counts, offsets, mdesc);
  fill_kernel<<<TT / 256, 256, 0, stream>>>(emeta, wmeta, offsets, fill, tlist, gwl);
  gemm1_kernel<<<dim3(II / 64, 39), 256, 0, stream>>>(xb, wgt, wut, offsets, mdesc, tlist, Abuf);
  gemm2_kernel<<<dim3(HH / 64, 39), 256, 0, stream>>>(Abuf, wdt, b_down, offsets, mdesc, tlist, gwl, out);
}

// Round 3
// 487.752 us; speedup vs baseline: 1.2388x; 1.0016x over previous
//
#include <hip/hip_runtime.h>
#include <math.h>

#define HD __device__ __forceinline__

constexpr int TT = 2048;   // tokens = B*S
constexpr int HH = 1024;   // hidden
constexpr int II = 2816;   // intermediate
constexpr int EE = 8;      // experts
constexpr int NK1 = HH / 64;     // 16 k-tiles for gemm1
constexpr int NK2 = II / 64;     // 44 k-tiles for gemm2
constexpr int KS2 = 2;           // gemm2 k-split
constexpr int HALF2 = NK2 / KS2; // 22
constexpr int MAXTILES = 40;     // max m-tile descriptors (8 + 4096/128)

typedef short  bf16x8  __attribute__((ext_vector_type(8)));
typedef float  floatx4 __attribute__((ext_vector_type(4)));

// ---- workspace layout (bytes) ----
constexpr size_t OFF_XB    = 0;                                // [TT][HH] bf16
constexpr size_t OFF_ABUF  = OFF_XB    + (size_t)TT*HH*2;      // [2T][I] bf16
constexpr size_t OFF_CNT   = OFF_ABUF  + (size_t)2*TT*II*2;
constexpr size_t OFF_OFFS  = OFF_CNT   + 256;
constexpr size_t OFF_MDESC = OFF_OFFS  + 256;                  // [1+40] int
constexpr size_t OFF_EMETA = OFF_MDESC + 256;                  // [T][2] int
constexpr size_t OFF_WMETA = OFF_EMETA + 16384;                // [T][2] float
constexpr size_t OFF_TLIST = OFF_WMETA + 16384;                // [2T] int
constexpr size_t OFF_GWL   = OFF_TLIST + 16384;                // [2T] float

HD unsigned short f2bf(float f) {
  union { float f; unsigned int u; } v; v.f = f;
  return (unsigned short)((v.u + 0x7fffu + ((v.u >> 16) & 1u)) >> 16);
}

HD float f4c(const float4& v, int nn) {
  return nn == 0 ? v.x : nn == 1 ? v.y : nn == 2 ? v.z : v.w;
}

HD void load_lds16(const void* gptr, void* lptr) {
  __builtin_amdgcn_global_load_lds(
      (const __attribute__((address_space(1))) void*)gptr,
      (__attribute__((address_space(3))) void*)lptr,
      16, 0, 0);
}

// load 8 float4 (8 k-rows x 4 n-cols) of a natural-layout weight tile
HD void load_w8(float4* wv, const float* wsrc, int k0, int wkg, int stride) {
#pragma unroll
  for (int j = 0; j < 8; ++j)
    wv[j] = *(const float4*)&wsrc[(size_t)(k0 + wkg * 8 + j) * stride];
}

// register-transpose 8k x 4n -> 4 ds_write_b128 into swizzled [n][k] LDS tile
HD void store_w8(const float4* wv, unsigned short* ldsT, int wng, int wkg) {
#pragma unroll
  for (int nn = 0; nn < 4; ++nn) {
    const int n = wng * 4 + nn;
    bf16x8 pk;
#pragma unroll
    for (int j = 0; j < 8; ++j) pk[j] = (short)f2bf(f4c(wv[j], nn));
    *(bf16x8*)&ldsT[n * 64 + ((wkg ^ (n & 7)) * 8)] = pk;
  }
}

// ---------------- prep: zero out + counts, convert x -> bf16 ----------------
__global__ __launch_bounds__(256)
void prep_kernel(const float* __restrict__ x, unsigned short* __restrict__ xb,
                 float* __restrict__ out, int* __restrict__ counts) {
  const int i = blockIdx.x * blockDim.x + threadIdx.x;   // 0 .. TT*HH/4-1
  if (i < EE) counts[i] = 0;
  const float4 z = {0.f, 0.f, 0.f, 0.f};
  ((float4*)out)[i] = z;
  float4 v = ((const float4*)x)[i];
  ushort4 o;
  o.x = f2bf(v.x); o.y = f2bf(v.y); o.z = f2bf(v.z); o.w = f2bf(v.w);
  ((ushort4*)xb)[i] = o;
}

// ---------------- router (fp32, exact top-k semantics) ----------------
__global__ __launch_bounds__(64)
void router_kernel(const float* __restrict__ x, const float* __restrict__ w_router,
                   int* __restrict__ counts, int* __restrict__ emeta, float* __restrict__ wmeta) {
  const int t = blockIdx.x;
  const int lane = threadIdx.x;
  float acc[EE];
#pragma unroll
  for (int e = 0; e < EE; ++e) acc[e] = 0.f;
  for (int h = lane; h < HH; h += 64) {
    const float xv = x[(size_t)t * HH + h];
    const float* wr = w_router + (size_t)h * EE;
#pragma unroll
    for (int e = 0; e < EE; ++e) acc[e] += xv * wr[e];
  }
#pragma unroll
  for (int e = 0; e < EE; ++e) {
#pragma unroll
    for (int off = 32; off > 0; off >>= 1) acc[e] += __shfl_xor(acc[e], off, 64);
  }
  if (lane == 0) {
    int e0 = 0; float v0 = acc[0];
#pragma unroll
    for (int e = 1; e < EE; ++e) if (acc[e] > v0) { v0 = acc[e]; e0 = e; }
    int e1 = -1; float v1 = -3.4e38f;
#pragma unroll
    for (int e = 0; e < EE; ++e) if (e != e0 && acc[e] > v1) { v1 = acc[e]; e1 = e; }
    const float ex = __expf(v1 - v0);
    const float s  = 1.f + ex;
    emeta[2 * t] = e0; emeta[2 * t + 1] = e1;
    wmeta[2 * t] = 1.f / s; wmeta[2 * t + 1] = ex / s;
    atomicAdd(&counts[e0], 1);
    atomicAdd(&counts[e1], 1);
  }
}

// ---------------- scan + fill + mdesc: ONE block ----------------
__global__ __launch_bounds__(256)
void scanfill_kernel(const int* __restrict__ counts, const int* __restrict__ emeta,
                     const float* __restrict__ wmeta,
                     int* __restrict__ offsets, int* __restrict__ mdesc,
                     int* __restrict__ token_list, float* __restrict__ gw_list) {
  __shared__ int s_off[EE];
  __shared__ int s_fill[EE];
  const int tid = threadIdx.x;
  if (tid < EE) s_fill[tid] = 0;
  if (tid == 0) {
    int s = 0;
    int nt = 0;
    for (int e = 0; e < EE; ++e) {
      const int c = counts[e];
      s_off[e] = s; offsets[e] = s;
      for (int m = 0; m < c; m += 128) mdesc[1 + nt++] = (e << 20) | m;
      s += c;
    }
    offsets[EE] = s;
    mdesc[0] = nt;
  }
  __syncthreads();
  for (int t = tid; t < TT; t += 256) {
#pragma unroll
    for (int s = 0; s < 2; ++s) {
      const int e = emeta[2 * t + s];
      const int pos = atomicAdd(&s_fill[e], 1);
      token_list[s_off[e] + pos] = t;
      gw_list[s_off[e] + pos] = wmeta[2 * t + s];
    }
  }
}

// ---------------- GEMM1: A = silu(X Wg) * (X Wu); fused fp32 weight transpose ----------------
__global__ __launch_bounds__(256, 3)
void gemm1_kernel(const unsigned short* __restrict__ xb,
                  const float* __restrict__ w_gate,   // [E][H][I] fp32 natural
                  const float* __restrict__ w_up,
                  const int* __restrict__ offsets,
                  const int* __restrict__ mdesc,
                  const int* __restrict__ token_list,
                  unsigned short* __restrict__ Abuf) {
  if ((int)blockIdx.y >= mdesc[0]) return;
  const int d = mdesc[1 + blockIdx.y];
  const int e = d >> 20;
  const int m_base = d & 0xFFFFF;
  const int off_e = offsets[e];
  const int n_e = offsets[e + 1] - off_e;
  const int n_base = blockIdx.x * 64;   // I dimension

  __shared__ __attribute__((aligned(16))) unsigned short ldsA[128 * 64];
  __shared__ __attribute__((aligned(16))) unsigned short ldsG[64 * 64];
  __shared__ __attribute__((aligned(16))) unsigned short ldsU[64 * 64];

  const int tid = threadIdx.x;
  const int wave = tid >> 6;
  const int lane = tid & 63;
  const int quad = lane >> 4;
  const int l16 = lane & 15;
  const int wave_m = (wave & 1) * 64;
  const int wave_n = (wave >> 1) * 32;

  const int srow = lane >> 3;               // 0..7
  const int clog = (lane & 7) ^ srow;       // xor-swizzled 16B chunk

  // A-staging pointers (gathered token rows)
  const unsigned short* gA[4];
#pragma unroll
  for (int it = 0; it < 4; ++it) {
    const int r = it * 32 + wave * 8 + srow;
    int ar = m_base + r; if (ar > n_e - 1) ar = n_e - 1;
    const int tok = token_list[off_e + ar];
    gA[it] = xb + (size_t)tok * HH + clog * 8;
  }

  // weight staging: 128 threads per tensor, 8k x 4n micro-tile each
  const int tt  = tid & 127;
  const int wng = tt & 15;        // n-group (4 cols of I)
  const int wkg = tt >> 4;        // k-group (8 rows of H)
  const float* wsrc = (tid < 128 ? w_gate : w_up) + (size_t)e * HH * II
                      + (size_t)(n_base + wng * 4);
  unsigned short* ldsT = (tid < 128 ? ldsG : ldsU);

  floatx4 accG[4][2], accU[4][2];
  const floatx4 fz = {0.f, 0.f, 0.f, 0.f};
#pragma unroll
  for (int i = 0; i < 4; ++i)
#pragma unroll
    for (int j = 0; j < 2; ++j) { accG[i][j] = fz; accU[i][j] = fz; }

  float4 wv[8];
  load_w8(wv, wsrc, 0, wkg, II);   // prefetch kt=0

  for (int kt = 0; kt < NK1; ++kt) {
    const int k0 = kt * 64;
#pragma unroll
    for (int it = 0; it < 4; ++it)
      load_lds16(gA[it] + k0, &ldsA[(it * 32 + wave * 8) * 64]);
    store_w8(wv, ldsT, wng, wkg);
    const int ktn = (kt + 1 < NK1) ? kt + 1 : kt;
    load_w8(wv, wsrc, ktn * 64, wkg, II);   // prefetch next (hidden behind MFMA)
    __syncthreads();
#pragma unroll
    for (int ks = 0; ks < 2; ++ks) {
      bf16x8 af[4], bg[2], bu[2];
#pragma unroll
      for (int f = 0; f < 4; ++f) {
        const int rowA = wave_m + f * 16 + l16;
        const int cA = (ks * 4 + quad) ^ (rowA & 7);
        af[f] = *(const bf16x8*)&ldsA[rowA * 64 + cA * 8];
      }
#pragma unroll
      for (int f = 0; f < 2; ++f) {
        const int rowB = wave_n + f * 16 + l16;
        const int cB = (ks * 4 + quad) ^ (rowB & 7);
        bg[f] = *(const bf16x8*)&ldsG[rowB * 64 + cB * 8];
        bu[f] = *(const bf16x8*)&ldsU[rowB * 64 + cB * 8];
      }
#pragma unroll
      for (int mf = 0; mf < 4; ++mf)
#pragma unroll
        for (int nf = 0; nf < 2; ++nf) {
          accG[mf][nf] = __builtin_amdgcn_mfma_f32_16x16x32_bf16(af[mf], bg[nf], accG[mf][nf], 0, 0, 0);
          accU[mf][nf] = __builtin_amdgcn_mfma_f32_16x16x32_bf16(af[mf], bu[nf], accU[mf][nf], 0, 0, 0);
        }
    }
    __syncthreads();
  }

#pragma unroll
  for (int mf = 0; mf < 4; ++mf)
#pragma unroll
    for (int nf = 0; nf < 2; ++nf) {
      const int col = n_base + wave_n + nf * 16 + l16;
#pragma unroll
      for (int j = 0; j < 4; ++j) {
        const int r = m_base + wave_m + mf * 16 + quad * 4 + j;
        if (r < n_e) {
          const float g = accG[mf][nf][j];
          const float u = accU[mf][nf][j];
          const float a = (g / (1.f + __expf(-g))) * u;
          Abuf[(size_t)(off_e + r) * II + col] = f2bf(a);
        }
      }
    }
}

// ---------------- GEMM2: Y = A Wd; fused fp32 weight transpose; k-split x2 ----------------
__global__ __launch_bounds__(256, 3)
void gemm2_kernel(const unsigned short* __restrict__ Abuf,
                  const float* __restrict__ w_down,   // [E][I][H] fp32 natural
                  const float* __restrict__ b_down,   // [E][H] fp32
                  const int* __restrict__ offsets,
                  const int* __restrict__ mdesc,
                  const int* __restrict__ token_list,
                  const float* __restrict__ gw_list,
                  float* __restrict__ out) {
  if ((int)blockIdx.y >= mdesc[0]) return;
  const int d = mdesc[1 + blockIdx.y];
  const int e = d >> 20;
  const int m_base = d & 0xFFFFF;
  const int off_e = offsets[e];
  const int n_e = offsets[e + 1] - off_e;
  const int n_base = blockIdx.x * 64;   // H dimension
  const int split = blockIdx.z;
  const int kt_lo = split * HALF2;
  const int kt_hi = kt_lo + HALF2;

  __shared__ __attribute__((aligned(16))) unsigned short ldsA[128 * 64];
  __shared__ __attribute__((aligned(16))) unsigned short ldsB[64 * 64];

  const int tid = threadIdx.x;
  const int wave = tid >> 6;
  const int lane = tid & 63;
  const int quad = lane >> 4;
  const int l16 = lane & 15;
  const int wave_m = (wave & 1) * 64;
  const int wave_n = (wave >> 1) * 32;

  const int srow = lane >> 3;
  const int clog = (lane & 7) ^ srow;

  const unsigned short* gA[4];
#pragma unroll
  for (int it = 0; it < 4; ++it) {
    const int r = it * 32 + wave * 8 + srow;
    int ar = m_base + r; if (ar > n_e - 1) ar = n_e - 1;
    gA[it] = Abuf + (size_t)(off_e + ar) * II + clog * 8;
  }

  const int wng = tid & 15;
  const int wkg = (tid >> 4) & 7;
  const float* wsrc = w_down + (size_t)e * II * HH + (size_t)(n_base + wng * 4);

  floatx4 acc[4][2];
  const floatx4 fz = {0.f, 0.f, 0.f, 0.f};
#pragma unroll
  for (int i = 0; i < 4; ++i)
#pragma unroll
    for (int j = 0; j < 2; ++j) acc[i][j] = fz;

  float4 wv[8];
  if (tid < 128) load_w8(wv, wsrc, kt_lo * 64, wkg, HH);

  for (int kt = kt_lo; kt < kt_hi; ++kt) {
    const int k0 = kt * 64;
#pragma unroll
    for (int it = 0; it < 4; ++it)
      load_lds16(gA[it] + k0, &ldsA[(it * 32 + wave * 8) * 64]);
    if (tid < 128) {
      store_w8(wv, ldsB, wng, wkg);
      const int ktn = (kt + 1 < kt_hi) ? kt + 1 : kt;
      load_w8(wv, wsrc, ktn * 64, wkg, HH);
    }
    __syncthreads();
#pragma unroll
    for (int ks = 0; ks < 2; ++ks) {
      bf16x8 af[4], bf[2];
#pragma unroll
      for (int f = 0; f < 4; ++f) {
        const int rowA = wave_m + f * 16 + l16;
        const int cA = (ks * 4 + quad) ^ (rowA & 7);
        af[f] = *(const bf16x8*)&ldsA[rowA * 64 + cA * 8];
      }
#pragma unroll
      for (int f = 0; f < 2; ++f) {
        const int rowB = wave_n + f * 16 + l16;
        const int cB = (ks * 4 + quad) ^ (rowB & 7);
        bf[f] = *(const bf16x8*)&ldsB[rowB * 64 + cB * 8];
      }
#pragma unroll
      for (int mf = 0; mf < 4; ++mf)
#pragma unroll
        for (int nf = 0; nf < 2; ++nf)
          acc[mf][nf] = __builtin_amdgcn_mfma_f32_16x16x32_bf16(af[mf], bf[nf], acc[mf][nf], 0, 0, 0);
    }
    __syncthreads();
  }

#pragma unroll
  for (int mf = 0; mf < 4; ++mf)
#pragma unroll
    for (int nf = 0; nf < 2; ++nf) {
      const int col = n_base + wave_n + nf * 16 + l16;
      const float bd = (split == 0) ? b_down[e * HH + col] : 0.f;
#pragma unroll
      for (int j = 0; j < 4; ++j) {
        const int r = m_base + wave_m + mf * 16 + quad * 4 + j;
        if (r < n_e) {
          const int cr = off_e + r;
          const int tok = token_list[cr];
          const float gw = gw_list[cr];
          atomicAdd(&out[(size_t)tok * HH + col], gw * (acc[mf][nf][j] + bd));
        }
      }
    }
}

// ---------------- launch ----------------
extern "C" void kernel_launch(void* const* d_in, const int* in_sizes, int n_in,
                              void* d_out, int out_size, void* d_ws, size_t ws_size,
                              hipStream_t stream) {
  const float* x        = (const float*)d_in[0];
  const float* w_router = (const float*)d_in[1];
  const float* w_gate   = (const float*)d_in[2];
  const float* w_up     = (const float*)d_in[3];
  const float* w_down   = (const float*)d_in[4];
  const float* b_down   = (const float*)d_in[5];
  float* out = (float*)d_out;

  char* ws = (char*)d_ws;
  unsigned short* xb   = (unsigned short*)(ws + OFF_XB);
  unsigned short* Abuf = (unsigned short*)(ws + OFF_ABUF);
  int*   counts  = (int*)(ws + OFF_CNT);
  int*   offsets = (int*)(ws + OFF_OFFS);
  int*   mdesc   = (int*)(ws + OFF_MDESC);
  int*   emeta   = (int*)(ws + OFF_EMETA);
  float* wmeta   = (float*)(ws + OFF_WMETA);
  int*   tlist   = (int*)(ws + OFF_TLIST);
  float* gwl     = (float*)(ws + OFF_GWL);

  prep_kernel<<<TT * HH / 4 / 256, 256, 0, stream>>>(x, xb, out, counts);
  router_kernel<<<TT, 64, 0, stream>>>(x, w_router, counts, emeta, wmeta);
  scanfill_kernel<<<1, 256, 0, stream>>>(counts, emeta, wmeta, offsets, mdesc, tlist, gwl);
  gemm1_kernel<<<dim3(II / 64, MAXTILES), 256, 0, stream>>>(xb, w_gate, w_up, offsets, mdesc, tlist, Abuf);
  gemm2_kernel<<<dim3(HH / 64, MAXTILES, KS2), 256, 0, stream>>>(Abuf, w_down, b_down, offsets, mdesc, tlist, gwl, out);
}